// Round 5
// baseline (364.810 us; speedup 1.0000x reference)
//
#include <hip/hip_runtime.h>
#include <hip/hip_bf16.h>

// Shapes (fixed by the reference)
#define L_DIM 4
#define N_DIM 2048
#define DIN   1024
#define H_DIM 8
#define DH    64
#define INNER 512   // H*DH

typedef __attribute__((ext_vector_type(8))) short short8;
typedef __attribute__((ext_vector_type(4))) float f32x4;

__device__ __forceinline__ unsigned short f2bf(float f) {
  unsigned u = __builtin_bit_cast(unsigned, f);
  u += 0x7fffu + ((u >> 16) & 1u);   // RNE
  return (unsigned short)(u >> 16);
}

// pack two positive floats to bf16x2 (round-half-up, <=0.5 ulp like RNE)
__device__ __forceinline__ unsigned pack2(float a, float b) {
  unsigned ua = __builtin_bit_cast(unsigned, a) + 0x8000u;
  unsigned ub = __builtin_bit_cast(unsigned, b) + 0x8000u;
  return (ua >> 16) | (ub & 0xffff0000u);
}

// async global->LDS, 16B per lane; lds base must be wave-uniform
typedef __attribute__((address_space(3))) unsigned int lds_uint;
typedef const __attribute__((address_space(1))) unsigned int glob_uint;
__device__ __forceinline__ void gl_lds16(const unsigned short* g,
                                         unsigned short* l) {
  __builtin_amdgcn_global_load_lds((glob_uint*)g, (lds_uint*)l, 16, 0, 0);
}

// ------------------------------------------------- fused casts + mask bias
__global__ void cast_all(const float* __restrict__ x,
                         const float* __restrict__ wq,
                         const float* __restrict__ wk,
                         const float* __restrict__ wv,
                         const float* __restrict__ wo,
                         unsigned short* __restrict__ xb,
                         unsigned short* __restrict__ w3,
                         unsigned short* __restrict__ wob,
                         const unsigned char* __restrict__ mraw,
                         float* __restrict__ bias) {
  __shared__ int votes[2];
  int bid = blockIdx.x, t = threadIdx.x;
  if (bid == 10240) {
    // mask -> additive bias (0 valid, -1e30 masked); dtype sniffed.
    if (t < 2) votes[t] = 0;
    __syncthreads();
    const unsigned int* m32 = (const unsigned int*)mraw;
    int anyf = 0, any8 = 0;
    for (int i = t; i < 2048; i += 256) {
      unsigned w = m32[i];
      if (w == 0x3f800000u) anyf = 1;
      if (w & 0xffffff00u) any8 = 1;
    }
    if (anyf) atomicOr(&votes[0], 1);
    if (any8) atomicOr(&votes[1], 1);
    __syncthreads();
    int fmt = votes[0] ? 2 : (votes[1] ? 1 : 0);
    for (int i = t; i < L_DIM * N_DIM; i += 256) {
      int mv;
      if (fmt == 2)      mv = ((const float*)mraw)[i] != 0.0f;
      else if (fmt == 1) mv = mraw[i] != 0;
      else               mv = ((const int*)mraw)[i] != 0;
      bias[i] = mv ? 0.0f : -1e30f;
    }
    return;
  }
  int i = (bid * 256 + t) * 4;
  const float* src; unsigned short* dst; int off;
  if (i < 8388608)      { src = x;  dst = xb;           off = i; }
  else if (i < 8912896) { src = wq; dst = w3;           off = i - 8388608; }
  else if (i < 9437184) { src = wk; dst = w3 + 524288;  off = i - 8912896; }
  else if (i < 9961472) { src = wv; dst = w3 + 1048576; off = i - 9437184; }
  else                  { src = wo; dst = wob;          off = i - 9961472; }
  float4 f = *(const float4*)(src + off);
  ushort4 o4;
  o4.x = f2bf(f.x); o4.y = f2bf(f.y); o4.z = f2bf(f.z); o4.w = f2bf(f.w);
  *(ushort4*)(dst + off) = o4;
}

// ---------------------------------------------------------------- QKV GEMM
// C[8192][1536] = Xb[8192][1024] @ W3^T. m97 pattern: global_load_lds w=16,
// unpadded LDS [row][32], BK=32. Epilogue: Q,K head-major [lh][n][64];
// V TRANSPOSED -> vT[lh][d][n].
__launch_bounds__(256, 2)
__global__ void gemm_qkv(const unsigned short* __restrict__ xb,
                         const unsigned short* __restrict__ w3,
                         unsigned short* __restrict__ qp,
                         unsigned short* __restrict__ kp,
                         unsigned short* __restrict__ vtp) {
  __shared__ unsigned short As[128 * 32];
  __shared__ unsigned short Bs[128 * 32];
  const int tid = threadIdx.x, lane = tid & 63, wid = tid >> 6;
  const int l16 = lane & 15, quad = lane >> 4;
  const int wm = wid >> 1, wn = wid & 1;
  const int m0 = blockIdx.x * 128, n0 = blockIdx.y * 128;

  f32x4 acc[4][4] = {};
  for (int kt = 0; kt < DIN; kt += 32) {
    __syncthreads();
#pragma unroll
    for (int it = 0; it < 2; ++it) {
      int c = it * 256 + wid * 64 + lane;
      int row = c >> 2, kseg = c & 3;
      unsigned short* lbase = &As[(it * 256 + wid * 64) * 8];
      gl_lds16(&xb[(m0 + row) * DIN + kt + kseg * 8], lbase);
      unsigned short* lbase2 = &Bs[(it * 256 + wid * 64) * 8];
      gl_lds16(&w3[(n0 + row) * DIN + kt + kseg * 8], lbase2);
    }
    __syncthreads();
    short8 af[4], bf[4];
#pragma unroll
    for (int mt = 0; mt < 4; ++mt)
      af[mt] = *(const short8*)&As[(wm * 64 + mt * 16 + l16) * 32 + quad * 8];
#pragma unroll
    for (int nt = 0; nt < 4; ++nt)
      bf[nt] = *(const short8*)&Bs[(wn * 64 + nt * 16 + l16) * 32 + quad * 8];
#pragma unroll
    for (int mt = 0; mt < 4; ++mt)
#pragma unroll
      for (int nt = 0; nt < 4; ++nt)
        acc[mt][nt] = __builtin_amdgcn_mfma_f32_16x16x32_bf16(
            af[mt], bf[nt], acc[mt][nt], 0, 0, 0);
  }
#pragma unroll
  for (int mt = 0; mt < 4; ++mt)
#pragma unroll
    for (int nt = 0; nt < 4; ++nt)
#pragma unroll
      for (int r = 0; r < 4; ++r) {
        int grow = m0 + wm * 64 + mt * 16 + quad * 4 + r;
        int gcol = n0 + wn * 64 + nt * 16 + l16;
        unsigned short bv = f2bf(acc[mt][nt][r]);
        int which = gcol >> 9, rr = gcol & 511;
        int h = rr >> 6, d = rr & 63;
        int l = grow >> 11, n = grow & 2047;
        if (which == 2)  // vT[lh][d][n]
          vtp[((size_t)(l * H_DIM + h) * DH + d) * N_DIM + n] = bv;
        else {
          unsigned short* dst = which ? kp : qp;
          dst[(((l * H_DIM + h) * N_DIM + n) * DH) + d] = bv;
        }
      }
}

// ---------------------------------------------------------------- attention
// Flash attention, fixed-max softmax (scores bounded; masked -> exp()==0).
// 64 q-rows/block (wave owns 16), 128-key tiles.
// NEW r5: (a) K fragments register-prefetched one tile ahead (the 16 b128
// loads for tile t+1 issue right after tile t's QK^T frees the regs; the
// ~500cyc softmax+PV section hides the latency). (b) XCD-aware 1D block
// swizzle: blocks b with b%8==x land on XCD x (round-robin dispatch);
// each XCD serves 4 lh values -> K/V working set 2MB, L2-resident.
// V staged to LDS (rotation swizzle, coalesced b128), P^T wave-private LDS.
#define PW_STRIDE 136  // shorts: 272B rows
__launch_bounds__(256, 3)
__global__ void attn_kernel(const unsigned short* __restrict__ qg,
                            const unsigned short* __restrict__ kg,
                            const unsigned short* __restrict__ vtg,
                            const float* __restrict__ bias,
                            unsigned short* __restrict__ aout) {
  __shared__ __align__(16) unsigned short Vs[64 * PW_STRIDE];  // 17.4 KB
  __shared__ __align__(16) unsigned short Pw[64 * PW_STRIDE];  // 17.4 KB
  const int tid = threadIdx.x, lane = tid & 63, wid = tid >> 6;
  const int l16 = lane & 15, quad = lane >> 4;
  // XCD swizzle: bid%8 = XCD (round-robin); each XCD owns 4 consecutive lh.
  const int bid = blockIdx.x;
  const int xcd = bid & 7, j = bid >> 3;      // j in 0..127
  const int lh = xcd * 4 + (j >> 5);          // 4 lh per XCD
  const int q0 = (j & 31) << 6;               // 32 q-tiles of 64
  const int l = lh >> 3, h = lh & 7;
  const unsigned short* Qb = qg + (size_t)lh * N_DIM * DH;
  const unsigned short* Kb = kg + (size_t)lh * N_DIM * DH;
  const unsigned short* Vt = vtg + (size_t)lh * DH * N_DIM;
  const float* bl = bias + l * N_DIM;
  unsigned short* pw_row = &Pw[(wid * 16 + l16) * PW_STRIDE];

  // V staging map: thread -> (d = p*16 + (tid>>4), gr = tid&15), p = 0..3
  const int vd = tid >> 4, vgr = tid & 15;

  // Q B-frag: B[k=dh][n=qrow], lane l16 = qrow (read once)
  short8 qf[2];
#pragma unroll
  for (int ks = 0; ks < 2; ++ks)
    qf[ks] = *(const short8*)&Qb[(q0 + wid * 16 + l16) * DH + ks * 32 +
                                 quad * 8];

  // preload tile 0's V and K into registers
  short8 vstg[4];
#pragma unroll
  for (int p = 0; p < 4; ++p)
    vstg[p] = *(const short8*)&Vt[(size_t)(p * 16 + vd) * N_DIM + vgr * 8];
  short8 kf[16];
#pragma unroll
  for (int nt = 0; nt < 8; ++nt)
#pragma unroll
    for (int ks = 0; ks < 2; ++ks)
      kf[nt * 2 + ks] =
          *(const short8*)&Kb[(nt * 16 + l16) * DH + ks * 32 + quad * 8];

  f32x4 o[4] = {};   // O C-layout: rows quad*4+r (qrow), col l16 (d)
  float lsum = 0.f;  // per-lane partial row-sum for qrow = l16

  for (int kv = 0; kv < N_DIM; kv += 128) {
    __syncthreads();  // all waves done reading Vs of prev tile
#pragma unroll
    for (int p = 0; p < 4; ++p) {
      int d = p * 16 + vd;
      int slot = (vgr + d) & 15;
      *(short8*)&Vs[d * PW_STRIDE + slot * 8] = vstg[p];
    }
    __syncthreads();  // Vs ready
    // prefetch next tile's V (lands during this tile's compute)
    if (kv + 128 < N_DIM) {
#pragma unroll
      for (int p = 0; p < 4; ++p)
        vstg[p] = *(const short8*)&Vt[(size_t)(p * 16 + vd) * N_DIM + kv +
                                      128 + vgr * 8];
    }

    // S^T tiles from the PREFETCHED kf: m=key (8 tiles of 16), n=qrow
    f32x4 sc[8] = {};
#pragma unroll
    for (int nt = 0; nt < 8; ++nt) {
      sc[nt] = __builtin_amdgcn_mfma_f32_16x16x32_bf16(kf[nt * 2], qf[0],
                                                       sc[nt], 0, 0, 0);
      sc[nt] = __builtin_amdgcn_mfma_f32_16x16x32_bf16(kf[nt * 2 + 1], qf[1],
                                                       sc[nt], 0, 0, 0);
    }
    // prefetch next tile's K into the now-free kf regs; softmax+PV hide it
    if (kv + 128 < N_DIM) {
#pragma unroll
      for (int nt = 0; nt < 8; ++nt)
#pragma unroll
        for (int ks = 0; ks < 2; ++ks)
          kf[nt * 2 + ks] = *(const short8*)&Kb[(kv + 128 + nt * 16 + l16) *
                                                    DH +
                                                ks * 32 + quad * 8];
    }
    // softmax + pack + stash into wave-private LDS
#pragma unroll
    for (int nt = 0; nt < 8; ++nt) {
      float4 b4 = *(const float4*)&bl[kv + nt * 16 + quad * 4];
      float p0 = __expf(fmaf(sc[nt][0], 0.125f, b4.x));
      float p1 = __expf(fmaf(sc[nt][1], 0.125f, b4.y));
      float p2 = __expf(fmaf(sc[nt][2], 0.125f, b4.z));
      float p3 = __expf(fmaf(sc[nt][3], 0.125f, b4.w));
      lsum += (p0 + p1) + (p2 + p3);
      uint2 pk = make_uint2(pack2(p0, p1), pack2(p2, p3));
      *(uint2*)&pw_row[nt * 16 + quad * 4] = pk;
    }
    // O += P V : A-frag P from wave-private LDS, B-frag V from swizzled Vs
#pragma unroll
    for (int g = 0; g < 4; ++g) {
      short8 pa = *(const short8*)&pw_row[g * 32 + quad * 8];
#pragma unroll
      for (int nt = 0; nt < 4; ++nt) {
        int d = nt * 16 + l16;
        int slot = (g * 4 + quad + d) & 15;
        short8 vb = *(const short8*)&Vs[d * PW_STRIDE + slot * 8];
        o[nt] = __builtin_amdgcn_mfma_f32_16x16x32_bf16(pa, vb, o[nt], 0, 0,
                                                        0);
      }
    }
  }
  // row-sums: reduce across the 4 quads holding the same qrow=l16
  lsum += __shfl_xor(lsum, 16);
  lsum += __shfl_xor(lsum, 32);
#pragma unroll
  for (int r = 0; r < 4; ++r) {
    float inv = 1.f / __shfl(lsum, quad * 4 + r);
    int row = q0 + wid * 16 + quad * 4 + r;
#pragma unroll
    for (int nt = 0; nt < 4; ++nt)
      aout[(size_t)(l * N_DIM + row) * INNER + h * DH + nt * 16 + l16] =
          f2bf(o[nt][r] * inv);
  }
}

// ---------------------------------------------------------------- out GEMM
// out[8192][1024] = attn[8192][512] @ Wo^T + bo (fp32 out), m97 pattern.
__launch_bounds__(256, 2)
__global__ void gemm_out(const unsigned short* __restrict__ a,
                         const unsigned short* __restrict__ wo,
                         const float* __restrict__ bo,
                         float* __restrict__ out) {
  __shared__ unsigned short As[128 * 32];
  __shared__ unsigned short Bs[128 * 32];
  const int tid = threadIdx.x, lane = tid & 63, wid = tid >> 6;
  const int l16 = lane & 15, quad = lane >> 4;
  const int wm = wid >> 1, wn = wid & 1;
  const int m0 = blockIdx.x * 128, n0 = blockIdx.y * 128;

  f32x4 acc[4][4] = {};
  for (int kt = 0; kt < INNER; kt += 32) {
    __syncthreads();
#pragma unroll
    for (int it = 0; it < 2; ++it) {
      int c = it * 256 + wid * 64 + lane;
      int row = c >> 2, kseg = c & 3;
      unsigned short* lbase = &As[(it * 256 + wid * 64) * 8];
      gl_lds16(&a[(m0 + row) * INNER + kt + kseg * 8], lbase);
      unsigned short* lbase2 = &Bs[(it * 256 + wid * 64) * 8];
      gl_lds16(&wo[(n0 + row) * INNER + kt + kseg * 8], lbase2);
    }
    __syncthreads();
    short8 af[4], bf[4];
#pragma unroll
    for (int mt = 0; mt < 4; ++mt)
      af[mt] = *(const short8*)&As[(wm * 64 + mt * 16 + l16) * 32 + quad * 8];
#pragma unroll
    for (int nt = 0; nt < 4; ++nt)
      bf[nt] = *(const short8*)&Bs[(wn * 64 + nt * 16 + l16) * 32 + quad * 8];
#pragma unroll
    for (int mt = 0; mt < 4; ++mt)
#pragma unroll
      for (int nt = 0; nt < 4; ++nt)
        acc[mt][nt] = __builtin_amdgcn_mfma_f32_16x16x32_bf16(
            af[mt], bf[nt], acc[mt][nt], 0, 0, 0);
  }
#pragma unroll
  for (int mt = 0; mt < 4; ++mt)
#pragma unroll
    for (int nt = 0; nt < 4; ++nt)
#pragma unroll
      for (int r = 0; r < 4; ++r) {
        int grow = m0 + wm * 64 + mt * 16 + quad * 4 + r;
        int gcol = n0 + wn * 64 + nt * 16 + l16;
        out[(size_t)grow * DIN + gcol] = acc[mt][nt][r] + bo[gcol];
      }
}

// ---------------------------------------------------------------- launch
extern "C" void kernel_launch(void* const* d_in, const int* in_sizes, int n_in,
                              void* d_out, int out_size, void* d_ws,
                              size_t ws_size, hipStream_t stream) {
  const float* x  = (const float*)d_in[0];
  const float* Wq = (const float*)d_in[1];
  const float* Wk = (const float*)d_in[2];
  const float* Wv = (const float*)d_in[3];
  const float* Wo = (const float*)d_in[4];
  const float* bo = (const float*)d_in[5];
  const unsigned char* mask = (const unsigned char*)d_in[6];
  float* out = (float*)d_out;

  char* ws = (char*)d_ws;
  unsigned short* xb  = (unsigned short*)(ws + 0);         // 16 MB
  unsigned short* w3  = (unsigned short*)(ws + 16777216);  // 3 MB
  unsigned short* wob = (unsigned short*)(ws + 19922944);  // 1 MB
  unsigned short* q   = (unsigned short*)(ws + 20971520);  // 8 MB
  unsigned short* k   = (unsigned short*)(ws + 29360128);  // 8 MB
  unsigned short* vt  = (unsigned short*)(ws + 37748736);  // 8 MB (transposed)
  unsigned short* att = (unsigned short*)(ws + 46137344);  // 8 MB
  float* bias         = (float*)(ws + 54525952);           // 32 KB

  cast_all<<<10241, 256, 0, stream>>>(x, Wq, Wk, Wv, Wo, xb, w3, wob, mask,
                                      bias);
  gemm_qkv<<<dim3(64, 12), 256, 0, stream>>>(xb, w3, q, k, vt);
  attn_kernel<<<1024, 256, 0, stream>>>(q, k, vt, bias, att);
  gemm_out<<<dim3(64, 8), 256, 0, stream>>>(att, wob, bo, out);
}

// Round 6
// 218.521 us; speedup vs baseline: 1.6695x; 1.6695x over previous
//
#include <hip/hip_runtime.h>
#include <hip/hip_bf16.h>

// Shapes (fixed by the reference)
#define L_DIM 4
#define N_DIM 2048
#define DIN   1024
#define H_DIM 8
#define DH    64
#define INNER 512   // H*DH

typedef __attribute__((ext_vector_type(8))) short short8;
typedef __attribute__((ext_vector_type(4))) float f32x4;

__device__ __forceinline__ unsigned short f2bf(float f) {
  unsigned u = __builtin_bit_cast(unsigned, f);
  u += 0x7fffu + ((u >> 16) & 1u);   // RNE
  return (unsigned short)(u >> 16);
}

// pack two positive floats to bf16x2 (round-half-up, <=0.5 ulp like RNE)
__device__ __forceinline__ unsigned pack2(float a, float b) {
  unsigned ua = __builtin_bit_cast(unsigned, a) + 0x8000u;
  unsigned ub = __builtin_bit_cast(unsigned, b) + 0x8000u;
  return (ua >> 16) | (ub & 0xffff0000u);
}

// async global->LDS, 16B per lane; lds base must be wave-uniform
typedef __attribute__((address_space(3))) unsigned int lds_uint;
typedef const __attribute__((address_space(1))) unsigned int glob_uint;
__device__ __forceinline__ void gl_lds16(const unsigned short* g,
                                         unsigned short* l) {
  __builtin_amdgcn_global_load_lds((glob_uint*)g, (lds_uint*)l, 16, 0, 0);
}

// ------------------------------------------------- fused casts + mask bias
__global__ void cast_all(const float* __restrict__ x,
                         const float* __restrict__ wq,
                         const float* __restrict__ wk,
                         const float* __restrict__ wv,
                         const float* __restrict__ wo,
                         unsigned short* __restrict__ xb,
                         unsigned short* __restrict__ w3,
                         unsigned short* __restrict__ wob,
                         const unsigned char* __restrict__ mraw,
                         float* __restrict__ bias) {
  __shared__ int votes[2];
  int bid = blockIdx.x, t = threadIdx.x;
  if (bid == 10240) {
    // mask -> additive bias (0 valid, -1e30 masked); dtype sniffed.
    if (t < 2) votes[t] = 0;
    __syncthreads();
    const unsigned int* m32 = (const unsigned int*)mraw;
    int anyf = 0, any8 = 0;
    for (int i = t; i < 2048; i += 256) {
      unsigned w = m32[i];
      if (w == 0x3f800000u) anyf = 1;
      if (w & 0xffffff00u) any8 = 1;
    }
    if (anyf) atomicOr(&votes[0], 1);
    if (any8) atomicOr(&votes[1], 1);
    __syncthreads();
    int fmt = votes[0] ? 2 : (votes[1] ? 1 : 0);
    for (int i = t; i < L_DIM * N_DIM; i += 256) {
      int mv;
      if (fmt == 2)      mv = ((const float*)mraw)[i] != 0.0f;
      else if (fmt == 1) mv = mraw[i] != 0;
      else               mv = ((const int*)mraw)[i] != 0;
      bias[i] = mv ? 0.0f : -1e30f;
    }
    return;
  }
  int i = (bid * 256 + t) * 4;
  const float* src; unsigned short* dst; int off;
  if (i < 8388608)      { src = x;  dst = xb;           off = i; }
  else if (i < 8912896) { src = wq; dst = w3;           off = i - 8388608; }
  else if (i < 9437184) { src = wk; dst = w3 + 524288;  off = i - 8912896; }
  else if (i < 9961472) { src = wv; dst = w3 + 1048576; off = i - 9437184; }
  else                  { src = wo; dst = wob;          off = i - 9961472; }
  float4 f = *(const float4*)(src + off);
  ushort4 o4;
  o4.x = f2bf(f.x); o4.y = f2bf(f.y); o4.z = f2bf(f.z); o4.w = f2bf(f.w);
  *(ushort4*)(dst + off) = o4;
}

// ---------------------------------------------------------------- QKV GEMM
// C[8192][1536] = Xb[8192][1024] @ W3^T. m97 pattern: global_load_lds w=16,
// unpadded LDS [row][32], BK=32. Epilogue: Q,K head-major [lh][n][64];
// V blocks (blockIdx.y>=8, whole tile is V) transpose through LDS and store
// vT[lh][d][n] with coalesced b128 (was a 2-byte stride-4KB scatter storm).
__launch_bounds__(256, 2)
__global__ void gemm_qkv(const unsigned short* __restrict__ xb,
                         const unsigned short* __restrict__ w3,
                         unsigned short* __restrict__ qp,
                         unsigned short* __restrict__ kp,
                         unsigned short* __restrict__ vtp) {
  __shared__ __align__(16) unsigned short Sh[8704];  // As|Bs staging, T reuse
  unsigned short* As = Sh;          // 128*32
  unsigned short* Bs = Sh + 4096;   // 128*32
  const int tid = threadIdx.x, lane = tid & 63, wid = tid >> 6;
  const int l16 = lane & 15, quad = lane >> 4;
  const int wm = wid >> 1, wn = wid & 1;
  const int m0 = blockIdx.x * 128, n0 = blockIdx.y * 128;

  f32x4 acc[4][4] = {};
  for (int kt = 0; kt < DIN; kt += 32) {
    __syncthreads();
#pragma unroll
    for (int it = 0; it < 2; ++it) {
      int c = it * 256 + wid * 64 + lane;
      int row = c >> 2, kseg = c & 3;
      unsigned short* lbase = &As[(it * 256 + wid * 64) * 8];
      gl_lds16(&xb[(m0 + row) * DIN + kt + kseg * 8], lbase);
      unsigned short* lbase2 = &Bs[(it * 256 + wid * 64) * 8];
      gl_lds16(&w3[(n0 + row) * DIN + kt + kseg * 8], lbase2);
    }
    __syncthreads();
    short8 af[4], bf[4];
#pragma unroll
    for (int mt = 0; mt < 4; ++mt)
      af[mt] = *(const short8*)&As[(wm * 64 + mt * 16 + l16) * 32 + quad * 8];
#pragma unroll
    for (int nt = 0; nt < 4; ++nt)
      bf[nt] = *(const short8*)&Bs[(wn * 64 + nt * 16 + l16) * 32 + quad * 8];
#pragma unroll
    for (int mt = 0; mt < 4; ++mt)
#pragma unroll
      for (int nt = 0; nt < 4; ++nt)
        acc[mt][nt] = __builtin_amdgcn_mfma_f32_16x16x32_bf16(
            af[mt], bf[nt], acc[mt][nt], 0, 0, 0);
  }
  if (blockIdx.y >= 8) {
    // whole 128x128 tile is V: transpose via LDS, store coalesced to vT
    const int l = m0 >> 11, mloc = m0 & 2047;
#pragma unroll
    for (int chunk = 0; chunk < 2; ++chunk) {
      __syncthreads();
      if (wn == chunk) {
#pragma unroll
        for (int mt = 0; mt < 4; ++mt)
#pragma unroll
          for (int nt = 0; nt < 4; ++nt) {
            int col = nt * 16 + l16;              // 0..63 within chunk
            int rowb = wm * 64 + mt * 16 + quad * 4;
            ushort4 pv;
            pv.x = f2bf(acc[mt][nt][0]);
            pv.y = f2bf(acc[mt][nt][1]);
            pv.z = f2bf(acc[mt][nt][2]);
            pv.w = f2bf(acc[mt][nt][3]);
            *(ushort4*)&Sh[col * 136 + rowb] = pv;
          }
      }
      __syncthreads();
      int hh = ((n0 + chunk * 64) & 511) >> 6;
#pragma unroll
      for (int it = 0; it < 4; ++it) {
        int c = it * 256 + tid;
        int cl = c >> 4, seg = c & 15;  // d = cl, n-seg
        short8 vv = *(const short8*)&Sh[cl * 136 + seg * 8];
        *(short8*)&vtp[((size_t)((l * H_DIM + hh) * DH + cl)) * N_DIM + mloc +
                       seg * 8] = vv;
      }
    }
  } else {
#pragma unroll
    for (int mt = 0; mt < 4; ++mt)
#pragma unroll
      for (int nt = 0; nt < 4; ++nt)
#pragma unroll
        for (int r = 0; r < 4; ++r) {
          int grow = m0 + wm * 64 + mt * 16 + quad * 4 + r;
          int gcol = n0 + wn * 64 + nt * 16 + l16;
          unsigned short bv = f2bf(acc[mt][nt][r]);
          int h = (gcol & 511) >> 6, d = gcol & 63;
          int l = grow >> 11, n = grow & 2047;
          unsigned short* dst = (gcol >> 9) ? kp : qp;
          dst[(((l * H_DIM + h) * N_DIM + n) * DH) + d] = bv;
        }
  }
}

// ---------------------------------------------------------------- attention
// m97-style DMA-staged flash attention, fixed-max softmax (scores bounded;
// masked -> exp()==0). 128 q-rows/block (wave owns 32), 128-key tiles,
// grid 512 = exactly 2 blocks/CU. K (16KB) and V^T (16KB) staged per tile
// via global_load_lds w=16 (8 DMA/thread, all in flight, ONE drain/tile —
// the latency-batching the compiler can't defeat, unlike reg prefetch which
// r5 proved gets sunk). Granule-rotation swizzles make every LDS access
// <=2-way. P^T stashed in wave-private rotation-swizzled LDS (no barrier).
// XCD swizzle keeps K/V L2-resident (r5: FETCH 72->12MB).
#define PW_S 128
__launch_bounds__(256, 2)
__global__ void attn_kernel(const unsigned short* __restrict__ qg,
                            const unsigned short* __restrict__ kg,
                            const unsigned short* __restrict__ vtg,
                            const float* __restrict__ bias,
                            unsigned short* __restrict__ aout) {
  __shared__ __align__(16) unsigned short Ks[128 * 64];   // 16 KB
  __shared__ __align__(16) unsigned short Vs[64 * 128];   // 16 KB
  __shared__ __align__(16) unsigned short Pw[128 * PW_S]; // 32 KB
  const int tid = threadIdx.x, lane = tid & 63, wid = tid >> 6;
  const int l16 = lane & 15, quad = lane >> 4;
  // XCD swizzle: bid%8 = XCD (round-robin dispatch); 4 lh per XCD.
  const int bid = blockIdx.x;
  const int xcd = bid & 7, j = bid >> 3;      // j in 0..63
  const int lh = xcd * 4 + (j >> 4);          // 16 q-blocks per lh
  const int q0 = (j & 15) << 7;               // q-tiles of 128
  const int l = lh >> 3, h = lh & 7;
  const unsigned short* Qb = qg + (size_t)lh * N_DIM * DH;
  const unsigned short* Kb = kg + (size_t)lh * N_DIM * DH;
  const unsigned short* Vt = vtg + (size_t)lh * DH * N_DIM;
  const float* bl = bias + l * N_DIM;

  // Q B-frags: B[k=dh][n=qrow], lane l16 = qrow (read once, 2 row-tiles)
  short8 qf[2][2];
#pragma unroll
  for (int mt = 0; mt < 2; ++mt)
#pragma unroll
    for (int ks = 0; ks < 2; ++ks)
      qf[mt][ks] = *(const short8*)&Qb[(q0 + wid * 32 + mt * 16 + l16) * DH +
                                       ks * 32 + quad * 8];

  f32x4 o[2][4] = {};              // O C-layout: row quad*4+r=qrow, col l16=d
  float lsum[2] = {0.f, 0.f};      // per-lane row-sum for qrow = l16

  for (int kv = 0; kv < N_DIM; kv += 128) {
    __syncthreads();  // everyone done reading Ks/Vs/Pw of prev tile
    // DMA-stage K[128 keys][64 dh] (granule rot by key) and
    // V^T[64 d][128 keys] (granule rot by d); LDS slots linear per lane.
#pragma unroll
    for (int it = 0; it < 4; ++it) {
      int cb = it * 256 + wid * 64;          // wave-uniform chunk base
      int c = cb + lane;
      int key = c >> 3, sl = c & 7, gs = (sl + key) & 7;
      gl_lds16(&Kb[(kv + key) * DH + gs * 8], &Ks[cb * 8]);
      int d = c >> 4, sv = c & 15, gv = (sv + d) & 15;
      gl_lds16(&Vt[(size_t)d * N_DIM + kv + gv * 8], &Vs[cb * 8]);
    }
    __syncthreads();  // single vmcnt drain for all 2048 DMAs

    // S^T = K Q : m=key (8 tiles), n=qrow (2 tiles of 16 per wave)
    f32x4 sc[2][8] = {};
#pragma unroll
    for (int nt = 0; nt < 8; ++nt)
#pragma unroll
      for (int ks = 0; ks < 2; ++ks) {
        int s = (ks * 4 + quad - l16) & 7;
        short8 kf = *(const short8*)&Ks[(nt * 16 + l16) * 64 + s * 8];
#pragma unroll
        for (int mt = 0; mt < 2; ++mt)
          sc[mt][nt] = __builtin_amdgcn_mfma_f32_16x16x32_bf16(
              kf, qf[mt][ks], sc[mt][nt], 0, 0, 0);
      }
    // softmax + pack + stash (wave-private rows, granule rot by l16)
#pragma unroll
    for (int mt = 0; mt < 2; ++mt) {
      unsigned short* pr = &Pw[(wid * 32 + mt * 16 + l16) * PW_S];
#pragma unroll
      for (int nt = 0; nt < 8; ++nt) {
        float4 b4 = *(const float4*)&bl[kv + nt * 16 + quad * 4];
        float p0 = __expf(fmaf(sc[mt][nt][0], 0.125f, b4.x));
        float p1 = __expf(fmaf(sc[mt][nt][1], 0.125f, b4.y));
        float p2 = __expf(fmaf(sc[mt][nt][2], 0.125f, b4.z));
        float p3 = __expf(fmaf(sc[mt][nt][3], 0.125f, b4.w));
        lsum[mt] += (p0 + p1) + (p2 + p3);
        uint2 pk = make_uint2(pack2(p0, p1), pack2(p2, p3));
        int gk = nt * 2 + (quad >> 1);            // 8-key granule
        int s = (gk + l16) & 15;
        *(uint2*)&pr[s * 8 + (quad & 1) * 4] = pk;
      }
    }
    // O += P V
#pragma unroll
    for (int g = 0; g < 4; ++g) {
      short8 pa[2];
#pragma unroll
      for (int mt = 0; mt < 2; ++mt) {
        int sp = (g * 4 + quad + l16) & 15;
        pa[mt] = *(const short8*)&Pw[(wid * 32 + mt * 16 + l16) * PW_S +
                                     sp * 8];
      }
#pragma unroll
      for (int nt = 0; nt < 4; ++nt) {
        int dd = nt * 16 + l16;
        int sv2 = (g * 4 + quad - l16) & 15;
        short8 vb = *(const short8*)&Vs[dd * 128 + sv2 * 8];
#pragma unroll
        for (int mt = 0; mt < 2; ++mt)
          o[mt][nt] = __builtin_amdgcn_mfma_f32_16x16x32_bf16(
              pa[mt], vb, o[mt][nt], 0, 0, 0);
      }
    }
  }
  // row-sums: reduce across the 4 quads holding the same qrow=l16
#pragma unroll
  for (int mt = 0; mt < 2; ++mt) {
    lsum[mt] += __shfl_xor(lsum[mt], 16);
    lsum[mt] += __shfl_xor(lsum[mt], 32);
  }
#pragma unroll
  for (int mt = 0; mt < 2; ++mt)
#pragma unroll
    for (int r = 0; r < 4; ++r) {
      float inv = 1.f / __shfl(lsum[mt], quad * 4 + r);
      int row = q0 + wid * 32 + mt * 16 + quad * 4 + r;
#pragma unroll
      for (int nt = 0; nt < 4; ++nt)
        aout[(size_t)(l * N_DIM + row) * INNER + h * DH + nt * 16 + l16] =
            f2bf(o[mt][nt][r] * inv);
    }
}

// ---------------------------------------------------------------- out GEMM
// out[8192][1024] = attn[8192][512] @ Wo^T + bo (fp32 out), m97 pattern.
__launch_bounds__(256, 2)
__global__ void gemm_out(const unsigned short* __restrict__ a,
                         const unsigned short* __restrict__ wo,
                         const float* __restrict__ bo,
                         float* __restrict__ out) {
  __shared__ unsigned short As[128 * 32];
  __shared__ unsigned short Bs[128 * 32];
  const int tid = threadIdx.x, lane = tid & 63, wid = tid >> 6;
  const int l16 = lane & 15, quad = lane >> 4;
  const int wm = wid >> 1, wn = wid & 1;
  const int m0 = blockIdx.x * 128, n0 = blockIdx.y * 128;

  f32x4 acc[4][4] = {};
  for (int kt = 0; kt < INNER; kt += 32) {
    __syncthreads();
#pragma unroll
    for (int it = 0; it < 2; ++it) {
      int c = it * 256 + wid * 64 + lane;
      int row = c >> 2, kseg = c & 3;
      unsigned short* lbase = &As[(it * 256 + wid * 64) * 8];
      gl_lds16(&a[(m0 + row) * INNER + kt + kseg * 8], lbase);
      unsigned short* lbase2 = &Bs[(it * 256 + wid * 64) * 8];
      gl_lds16(&wo[(n0 + row) * INNER + kt + kseg * 8], lbase2);
    }
    __syncthreads();
    short8 af[4], bf[4];
#pragma unroll
    for (int mt = 0; mt < 4; ++mt)
      af[mt] = *(const short8*)&As[(wm * 64 + mt * 16 + l16) * 32 + quad * 8];
#pragma unroll
    for (int nt = 0; nt < 4; ++nt)
      bf[nt] = *(const short8*)&Bs[(wn * 64 + nt * 16 + l16) * 32 + quad * 8];
#pragma unroll
    for (int mt = 0; mt < 4; ++mt)
#pragma unroll
      for (int nt = 0; nt < 4; ++nt)
        acc[mt][nt] = __builtin_amdgcn_mfma_f32_16x16x32_bf16(
            af[mt], bf[nt], acc[mt][nt], 0, 0, 0);
  }
#pragma unroll
  for (int mt = 0; mt < 4; ++mt)
#pragma unroll
    for (int nt = 0; nt < 4; ++nt)
#pragma unroll
      for (int r = 0; r < 4; ++r) {
        int grow = m0 + wm * 64 + mt * 16 + quad * 4 + r;
        int gcol = n0 + wn * 64 + nt * 16 + l16;
        out[(size_t)grow * DIN + gcol] = acc[mt][nt][r] + bo[gcol];
      }
}

// ---------------------------------------------------------------- launch
extern "C" void kernel_launch(void* const* d_in, const int* in_sizes, int n_in,
                              void* d_out, int out_size, void* d_ws,
                              size_t ws_size, hipStream_t stream) {
  const float* x  = (const float*)d_in[0];
  const float* Wq = (const float*)d_in[1];
  const float* Wk = (const float*)d_in[2];
  const float* Wv = (const float*)d_in[3];
  const float* Wo = (const float*)d_in[4];
  const float* bo = (const float*)d_in[5];
  const unsigned char* mask = (const unsigned char*)d_in[6];
  float* out = (float*)d_out;

  char* ws = (char*)d_ws;
  unsigned short* xb  = (unsigned short*)(ws + 0);         // 16 MB
  unsigned short* w3  = (unsigned short*)(ws + 16777216);  // 3 MB
  unsigned short* wob = (unsigned short*)(ws + 19922944);  // 1 MB
  unsigned short* q   = (unsigned short*)(ws + 20971520);  // 8 MB
  unsigned short* k   = (unsigned short*)(ws + 29360128);  // 8 MB
  unsigned short* vt  = (unsigned short*)(ws + 37748736);  // 8 MB (transposed)
  unsigned short* att = (unsigned short*)(ws + 46137344);  // 8 MB
  float* bias         = (float*)(ws + 54525952);           // 32 KB

  cast_all<<<10241, 256, 0, stream>>>(x, Wq, Wk, Wv, Wo, xb, w3, wob, mask,
                                      bias);
  gemm_qkv<<<dim3(64, 12), 256, 0, stream>>>(xb, w3, q, k, vt);
  attn_kernel<<<512, 256, 0, stream>>>(q, k, vt, bias, att);
  gemm_out<<<dim3(64, 8), 256, 0, stream>>>(att, wob, bo, out);
}

// Round 7
// 212.749 us; speedup vs baseline: 1.7147x; 1.0271x over previous
//
#include <hip/hip_runtime.h>
#include <hip/hip_bf16.h>

// Shapes (fixed by the reference)
#define L_DIM 4
#define N_DIM 2048
#define DIN   1024
#define H_DIM 8
#define DH    64
#define INNER 512   // H*DH

typedef __attribute__((ext_vector_type(8))) short short8;
typedef __attribute__((ext_vector_type(4))) float f32x4;

__device__ __forceinline__ unsigned short f2bf(float f) {
  unsigned u = __builtin_bit_cast(unsigned, f);
  u += 0x7fffu + ((u >> 16) & 1u);   // RNE
  return (unsigned short)(u >> 16);
}

// pack two positive floats to bf16x2 (round-half-up, <=0.5 ulp like RNE)
__device__ __forceinline__ unsigned pack2(float a, float b) {
  unsigned ua = __builtin_bit_cast(unsigned, a) + 0x8000u;
  unsigned ub = __builtin_bit_cast(unsigned, b) + 0x8000u;
  return (ua >> 16) | (ub & 0xffff0000u);
}

// async global->LDS, 16B per lane; lds base must be wave-uniform
typedef __attribute__((address_space(3))) unsigned int lds_uint;
typedef const __attribute__((address_space(1))) unsigned int glob_uint;
__device__ __forceinline__ void gl_lds16(const unsigned short* g,
                                         unsigned short* l) {
  __builtin_amdgcn_global_load_lds((glob_uint*)g, (lds_uint*)l, 16, 0, 0);
}

// ------------------------------------------------- fused casts + mask bias
__global__ void cast_all(const float* __restrict__ x,
                         const float* __restrict__ wq,
                         const float* __restrict__ wk,
                         const float* __restrict__ wv,
                         const float* __restrict__ wo,
                         unsigned short* __restrict__ xb,
                         unsigned short* __restrict__ w3,
                         unsigned short* __restrict__ wob,
                         const unsigned char* __restrict__ mraw,
                         float* __restrict__ bias) {
  __shared__ int votes[2];
  int bid = blockIdx.x, t = threadIdx.x;
  if (bid == 10240) {
    // mask -> additive bias (0 valid, -1e30 masked); dtype sniffed.
    if (t < 2) votes[t] = 0;
    __syncthreads();
    const unsigned int* m32 = (const unsigned int*)mraw;
    int anyf = 0, any8 = 0;
    for (int i = t; i < 2048; i += 256) {
      unsigned w = m32[i];
      if (w == 0x3f800000u) anyf = 1;
      if (w & 0xffffff00u) any8 = 1;
    }
    if (anyf) atomicOr(&votes[0], 1);
    if (any8) atomicOr(&votes[1], 1);
    __syncthreads();
    int fmt = votes[0] ? 2 : (votes[1] ? 1 : 0);
    for (int i = t; i < L_DIM * N_DIM; i += 256) {
      int mv;
      if (fmt == 2)      mv = ((const float*)mraw)[i] != 0.0f;
      else if (fmt == 1) mv = mraw[i] != 0;
      else               mv = ((const int*)mraw)[i] != 0;
      bias[i] = mv ? 0.0f : -1e30f;
    }
    return;
  }
  int i = (bid * 256 + t) * 4;
  const float* src; unsigned short* dst; int off;
  if (i < 8388608)      { src = x;  dst = xb;           off = i; }
  else if (i < 8912896) { src = wq; dst = w3;           off = i - 8388608; }
  else if (i < 9437184) { src = wk; dst = w3 + 524288;  off = i - 8912896; }
  else if (i < 9961472) { src = wv; dst = w3 + 1048576; off = i - 9437184; }
  else                  { src = wo; dst = wob;          off = i - 9961472; }
  float4 f = *(const float4*)(src + off);
  ushort4 o4;
  o4.x = f2bf(f.x); o4.y = f2bf(f.y); o4.z = f2bf(f.z); o4.w = f2bf(f.w);
  *(ushort4*)(dst + off) = o4;
}

// ---------------------------------------------------------------- QKV GEMM
// C[8192][1536] = Xb[8192][1024] @ W3^T. m97 pattern: global_load_lds w=16,
// unpadded LDS [row][32], BK=32. launch_bounds(256,3): VGPR<=168 -> 3
// blocks/CU (m97's operating point). Epilogue: Q,K head-major [lh][n][64];
// V blocks (blockIdx.y>=8) transpose through LDS, store vT coalesced b128.
__launch_bounds__(256, 3)
__global__ void gemm_qkv(const unsigned short* __restrict__ xb,
                         const unsigned short* __restrict__ w3,
                         unsigned short* __restrict__ qp,
                         unsigned short* __restrict__ kp,
                         unsigned short* __restrict__ vtp) {
  __shared__ __align__(16) unsigned short Sh[8704];  // As|Bs staging, T reuse
  unsigned short* As = Sh;          // 128*32
  unsigned short* Bs = Sh + 4096;   // 128*32
  const int tid = threadIdx.x, lane = tid & 63, wid = tid >> 6;
  const int l16 = lane & 15, quad = lane >> 4;
  const int wm = wid >> 1, wn = wid & 1;
  const int m0 = blockIdx.x * 128, n0 = blockIdx.y * 128;

  f32x4 acc[4][4] = {};
  for (int kt = 0; kt < DIN; kt += 32) {
    __syncthreads();
#pragma unroll
    for (int it = 0; it < 2; ++it) {
      int c = it * 256 + wid * 64 + lane;
      int row = c >> 2, kseg = c & 3;
      unsigned short* lbase = &As[(it * 256 + wid * 64) * 8];
      gl_lds16(&xb[(m0 + row) * DIN + kt + kseg * 8], lbase);
      unsigned short* lbase2 = &Bs[(it * 256 + wid * 64) * 8];
      gl_lds16(&w3[(n0 + row) * DIN + kt + kseg * 8], lbase2);
    }
    __syncthreads();
    short8 af[4], bf[4];
#pragma unroll
    for (int mt = 0; mt < 4; ++mt)
      af[mt] = *(const short8*)&As[(wm * 64 + mt * 16 + l16) * 32 + quad * 8];
#pragma unroll
    for (int nt = 0; nt < 4; ++nt)
      bf[nt] = *(const short8*)&Bs[(wn * 64 + nt * 16 + l16) * 32 + quad * 8];
#pragma unroll
    for (int mt = 0; mt < 4; ++mt)
#pragma unroll
      for (int nt = 0; nt < 4; ++nt)
        acc[mt][nt] = __builtin_amdgcn_mfma_f32_16x16x32_bf16(
            af[mt], bf[nt], acc[mt][nt], 0, 0, 0);
  }
  if (blockIdx.y >= 8) {
    // whole 128x128 tile is V: transpose via LDS, store coalesced to vT
    const int l = m0 >> 11, mloc = m0 & 2047;
#pragma unroll
    for (int chunk = 0; chunk < 2; ++chunk) {
      __syncthreads();
      if (wn == chunk) {
#pragma unroll
        for (int mt = 0; mt < 4; ++mt)
#pragma unroll
          for (int nt = 0; nt < 4; ++nt) {
            int col = nt * 16 + l16;              // 0..63 within chunk
            int rowb = wm * 64 + mt * 16 + quad * 4;
            ushort4 pv;
            pv.x = f2bf(acc[mt][nt][0]);
            pv.y = f2bf(acc[mt][nt][1]);
            pv.z = f2bf(acc[mt][nt][2]);
            pv.w = f2bf(acc[mt][nt][3]);
            *(ushort4*)&Sh[col * 136 + rowb] = pv;
          }
      }
      __syncthreads();
      int hh = ((n0 + chunk * 64) & 511) >> 6;
#pragma unroll
      for (int it = 0; it < 4; ++it) {
        int c = it * 256 + tid;
        int cl = c >> 4, seg = c & 15;  // d = cl, n-seg
        short8 vv = *(const short8*)&Sh[cl * 136 + seg * 8];
        *(short8*)&vtp[((size_t)((l * H_DIM + hh) * DH + cl)) * N_DIM + mloc +
                       seg * 8] = vv;
      }
    }
  } else {
#pragma unroll
    for (int mt = 0; mt < 4; ++mt)
#pragma unroll
      for (int nt = 0; nt < 4; ++nt)
#pragma unroll
        for (int r = 0; r < 4; ++r) {
          int grow = m0 + wm * 64 + mt * 16 + quad * 4 + r;
          int gcol = n0 + wn * 64 + nt * 16 + l16;
          unsigned short bv = f2bf(acc[mt][nt][r]);
          int h = (gcol & 511) >> 6, d = gcol & 63;
          int l = grow >> 11, n = grow & 2047;
          unsigned short* dst = (gcol >> 9) ? kp : qp;
          dst[(((l * H_DIM + h) * N_DIM + n) * DH) + d] = bv;
        }
  }
}

// ---------------------------------------------------------------- attention
// DMA-staged flash attention with DOUBLE-BUFFERED K/V staging:
// one barrier per tile; the tile t+1 DMA issues right after the barrier and
// has the whole compute phase to land, so the next barrier's vmcnt(0) drain
// costs ~0 (r6 exposed the full L2->LDS transfer between back-to-back
// barriers). PV runs in two 64-key halves reusing a 16KB wave-private Pw
// (wave-internal ordering, no barrier) -> LDS total 80KB = 2 blocks/CU.
// Fixed-max softmax (scores bounded; masked -> exp()==0). Granule-rotation
// swizzles keep LDS accesses uniform (r6-verified). XCD swizzle keeps K/V
// L2-resident (r5: FETCH 72->12MB).
#define PW_S 64
__launch_bounds__(256, 2)
__global__ void attn_kernel(const unsigned short* __restrict__ qg,
                            const unsigned short* __restrict__ kg,
                            const unsigned short* __restrict__ vtg,
                            const float* __restrict__ bias,
                            unsigned short* __restrict__ aout) {
  __shared__ __align__(16) unsigned short Ks[2][128 * 64];   // 2x16 KB
  __shared__ __align__(16) unsigned short Vs[2][64 * 128];   // 2x16 KB
  __shared__ __align__(16) unsigned short Pw[128 * PW_S];    // 16 KB
  const int tid = threadIdx.x, lane = tid & 63, wid = tid >> 6;
  const int l16 = lane & 15, quad = lane >> 4;
  // XCD swizzle: bid%8 = XCD (round-robin dispatch); 4 lh per XCD.
  const int bid = blockIdx.x;
  const int xcd = bid & 7, j = bid >> 3;      // j in 0..63
  const int lh = xcd * 4 + (j >> 4);          // 16 q-blocks per lh
  const int q0 = (j & 15) << 7;               // q-tiles of 128
  const int l = lh >> 3, h = lh & 7;
  const unsigned short* Qb = qg + (size_t)lh * N_DIM * DH;
  const unsigned short* Kb = kg + (size_t)lh * N_DIM * DH;
  const unsigned short* Vt = vtg + (size_t)lh * DH * N_DIM;
  const float* bl = bias + l * N_DIM;

  // Q B-frags: B[k=dh][n=qrow], lane l16 = qrow (read once, 2 row-tiles)
  short8 qf[2][2];
#pragma unroll
  for (int mt = 0; mt < 2; ++mt)
#pragma unroll
    for (int ks = 0; ks < 2; ++ks)
      qf[mt][ks] = *(const short8*)&Qb[(q0 + wid * 32 + mt * 16 + l16) * DH +
                                       ks * 32 + quad * 8];

  f32x4 o[2][4] = {};              // O C-layout: row quad*4+r=qrow, col l16=d
  float lsum[2] = {0.f, 0.f};      // per-lane row-sum for qrow = l16

  // stage tile 0 into buffer 0
#pragma unroll
  for (int it = 0; it < 4; ++it) {
    int cb = it * 256 + wid * 64;
    int c = cb + lane;
    int key = c >> 3, sl = c & 7, gs = (sl + key) & 7;
    gl_lds16(&Kb[key * DH + gs * 8], &Ks[0][cb * 8]);
    int d = c >> 4, sv = c & 15, gv = (sv + d) & 15;
    gl_lds16(&Vt[(size_t)d * N_DIM + gv * 8], &Vs[0][cb * 8]);
  }

  for (int t = 0; t < 16; ++t) {
    const int kv = t << 7, buf = t & 1;
    __syncthreads();  // vmcnt(0) drain: buf's DMA (issued last iter) landed;
                      // everyone done reading buf^1 from tile t-1
    if (t < 15) {     // issue tile t+1's DMA into the other buffer NOW
      int kv2 = kv + 128, b2 = buf ^ 1;
#pragma unroll
      for (int it = 0; it < 4; ++it) {
        int cb = it * 256 + wid * 64;
        int c = cb + lane;
        int key = c >> 3, sl = c & 7, gs = (sl + key) & 7;
        gl_lds16(&Kb[(kv2 + key) * DH + gs * 8], &Ks[b2][cb * 8]);
        int d = c >> 4, sv = c & 15, gv = (sv + d) & 15;
        gl_lds16(&Vt[(size_t)d * N_DIM + kv2 + gv * 8], &Vs[b2][cb * 8]);
      }
    }
    const unsigned short* Kst = Ks[buf];
    const unsigned short* Vst = Vs[buf];

#pragma unroll
    for (int hf = 0; hf < 2; ++hf) {  // two 64-key halves, Pw reused
      // S^T = K Q : m=key (4 tiles of 16), n=qrow (2 tiles per wave)
      f32x4 sc[2][4] = {};
#pragma unroll
      for (int nt = 0; nt < 4; ++nt)
#pragma unroll
        for (int ks = 0; ks < 2; ++ks) {
          int s = (ks * 4 + quad - l16) & 7;
          short8 kf = *(const short8*)&Kst[(hf * 64 + nt * 16 + l16) * 64 +
                                           s * 8];
#pragma unroll
          for (int mt = 0; mt < 2; ++mt)
            sc[mt][nt] = __builtin_amdgcn_mfma_f32_16x16x32_bf16(
                kf, qf[mt][ks], sc[mt][nt], 0, 0, 0);
        }
      // softmax + pack + stash (wave-private rows, granule rot by l16)
#pragma unroll
      for (int mt = 0; mt < 2; ++mt) {
        unsigned short* pr = &Pw[(wid * 32 + mt * 16 + l16) * PW_S];
#pragma unroll
        for (int nt = 0; nt < 4; ++nt) {
          float4 b4 = *(const float4*)&bl[kv + hf * 64 + nt * 16 + quad * 4];
          float p0 = __expf(fmaf(sc[mt][nt][0], 0.125f, b4.x));
          float p1 = __expf(fmaf(sc[mt][nt][1], 0.125f, b4.y));
          float p2 = __expf(fmaf(sc[mt][nt][2], 0.125f, b4.z));
          float p3 = __expf(fmaf(sc[mt][nt][3], 0.125f, b4.w));
          lsum[mt] += (p0 + p1) + (p2 + p3);
          uint2 pk = make_uint2(pack2(p0, p1), pack2(p2, p3));
          int gk = nt * 2 + (quad >> 1);          // 8-key granule in half
          int s = (gk + l16) & 7;
          *(uint2*)&pr[s * 8 + (quad & 1) * 4] = pk;
        }
      }
      // O += P V over this half's 64 keys (2 chunks of 32)
#pragma unroll
      for (int g = 0; g < 2; ++g) {
        short8 pa[2];
#pragma unroll
        for (int mt = 0; mt < 2; ++mt) {
          int sp = (g * 4 + quad + l16) & 7;
          pa[mt] = *(const short8*)&Pw[(wid * 32 + mt * 16 + l16) * PW_S +
                                       sp * 8];
        }
#pragma unroll
        for (int nt = 0; nt < 4; ++nt) {
          int dd = nt * 16 + l16;
          int sv2 = (hf * 8 + g * 4 + quad - l16) & 15;
          short8 vb = *(const short8*)&Vst[dd * 128 + sv2 * 8];
#pragma unroll
          for (int mt = 0; mt < 2; ++mt)
            o[mt][nt] = __builtin_amdgcn_mfma_f32_16x16x32_bf16(
                pa[mt], vb, o[mt][nt], 0, 0, 0);
        }
      }
    }
  }
  // row-sums: reduce across the 4 quads holding the same qrow=l16
#pragma unroll
  for (int mt = 0; mt < 2; ++mt) {
    lsum[mt] += __shfl_xor(lsum[mt], 16);
    lsum[mt] += __shfl_xor(lsum[mt], 32);
  }
#pragma unroll
  for (int mt = 0; mt < 2; ++mt)
#pragma unroll
    for (int r = 0; r < 4; ++r) {
      float inv = 1.f / __shfl(lsum[mt], quad * 4 + r);
      int row = q0 + wid * 32 + mt * 16 + quad * 4 + r;
#pragma unroll
      for (int nt = 0; nt < 4; ++nt)
        aout[(size_t)(l * N_DIM + row) * INNER + h * DH + nt * 16 + l16] =
            f2bf(o[mt][nt][r] * inv);
    }
}

// ---------------------------------------------------------------- out GEMM
// out[8192][1024] = attn[8192][512] @ Wo^T + bo (fp32 out), m97 pattern.
__launch_bounds__(256, 3)
__global__ void gemm_out(const unsigned short* __restrict__ a,
                         const unsigned short* __restrict__ wo,
                         const float* __restrict__ bo,
                         float* __restrict__ out) {
  __shared__ unsigned short As[128 * 32];
  __shared__ unsigned short Bs[128 * 32];
  const int tid = threadIdx.x, lane = tid & 63, wid = tid >> 6;
  const int l16 = lane & 15, quad = lane >> 4;
  const int wm = wid >> 1, wn = wid & 1;
  const int m0 = blockIdx.x * 128, n0 = blockIdx.y * 128;

  f32x4 acc[4][4] = {};
  for (int kt = 0; kt < INNER; kt += 32) {
    __syncthreads();
#pragma unroll
    for (int it = 0; it < 2; ++it) {
      int c = it * 256 + wid * 64 + lane;
      int row = c >> 2, kseg = c & 3;
      unsigned short* lbase = &As[(it * 256 + wid * 64) * 8];
      gl_lds16(&a[(m0 + row) * INNER + kt + kseg * 8], lbase);
      unsigned short* lbase2 = &Bs[(it * 256 + wid * 64) * 8];
      gl_lds16(&wo[(n0 + row) * INNER + kt + kseg * 8], lbase2);
    }
    __syncthreads();
    short8 af[4], bf[4];
#pragma unroll
    for (int mt = 0; mt < 4; ++mt)
      af[mt] = *(const short8*)&As[(wm * 64 + mt * 16 + l16) * 32 + quad * 8];
#pragma unroll
    for (int nt = 0; nt < 4; ++nt)
      bf[nt] = *(const short8*)&Bs[(wn * 64 + nt * 16 + l16) * 32 + quad * 8];
#pragma unroll
    for (int mt = 0; mt < 4; ++mt)
#pragma unroll
      for (int nt = 0; nt < 4; ++nt)
        acc[mt][nt] = __builtin_amdgcn_mfma_f32_16x16x32_bf16(
            af[mt], bf[nt], acc[mt][nt], 0, 0, 0);
  }
#pragma unroll
  for (int mt = 0; mt < 4; ++mt)
#pragma unroll
    for (int nt = 0; nt < 4; ++nt)
#pragma unroll
      for (int r = 0; r < 4; ++r) {
        int grow = m0 + wm * 64 + mt * 16 + quad * 4 + r;
        int gcol = n0 + wn * 64 + nt * 16 + l16;
        out[(size_t)grow * DIN + gcol] = acc[mt][nt][r] + bo[gcol];
      }
}

// ---------------------------------------------------------------- launch
extern "C" void kernel_launch(void* const* d_in, const int* in_sizes, int n_in,
                              void* d_out, int out_size, void* d_ws,
                              size_t ws_size, hipStream_t stream) {
  const float* x  = (const float*)d_in[0];
  const float* Wq = (const float*)d_in[1];
  const float* Wk = (const float*)d_in[2];
  const float* Wv = (const float*)d_in[3];
  const float* Wo = (const float*)d_in[4];
  const float* bo = (const float*)d_in[5];
  const unsigned char* mask = (const unsigned char*)d_in[6];
  float* out = (float*)d_out;

  char* ws = (char*)d_ws;
  unsigned short* xb  = (unsigned short*)(ws + 0);         // 16 MB
  unsigned short* w3  = (unsigned short*)(ws + 16777216);  // 3 MB
  unsigned short* wob = (unsigned short*)(ws + 19922944);  // 1 MB
  unsigned short* q   = (unsigned short*)(ws + 20971520);  // 8 MB
  unsigned short* k   = (unsigned short*)(ws + 29360128);  // 8 MB
  unsigned short* vt  = (unsigned short*)(ws + 37748736);  // 8 MB (transposed)
  unsigned short* att = (unsigned short*)(ws + 46137344);  // 8 MB
  float* bias         = (float*)(ws + 54525952);           // 32 KB

  cast_all<<<10241, 256, 0, stream>>>(x, Wq, Wk, Wv, Wo, xb, w3, wob, mask,
                                      bias);
  gemm_qkv<<<dim3(64, 12), 256, 0, stream>>>(xb, w3, q, k, vt);
  attn_kernel<<<512, 256, 0, stream>>>(q, k, vt, bias, att);
  gemm_out<<<dim3(64, 8), 256, 0, stream>>>(att, wob, bo, out);
}